// Round 6
// baseline (364.984 us; speedup 1.0000x reference)
//
#include <hip/hip_runtime.h>

#define KK 16
#define DD 15          // K-1
#define NPIX (2048*2048)

#define NBLK 1024      // 4 blocks/CU resident (matches (256,4) VGPR cap)
#define NTHR 256
#define ITERS (NPIX / (2 * NBLK * NTHR))   // 8 pixel-pairs per thread

typedef float v2f __attribute__((ext_vector_type(2)));

__global__ __launch_bounds__(NTHR, 4) void gum_kernel(
    const float* __restrict__ z,      // (DD, NPIX)
    const float* __restrict__ vert,   // (KK, DD) row-major
    float* __restrict__ out)          // [0,NPIX) = X as float, [NPIX,2*NPIX) = dmin
{
    // Only ||v_k||^2 in LDS (broadcast read). Vertex components stay
    // uniform-indexed -> s_load -> SGPR operand folded into v_pk_fma.
    __shared__ float vvS[KK];

    const int t = threadIdx.x;
    if (t < KK) {
        float s = 0.0f;
        #pragma unroll
        for (int d = 0; d < DD; ++d) {
            float v = vert[t * DD + d];
            s += v * v;
        }
        vvS[t] = s;
    }
    __syncthreads();

    const size_t stride = (size_t)NBLK * NTHR * 2;          // px per grid step
    size_t base = ((size_t)blockIdx.x * NTHR + t) * 2;

    // Software pipeline: keep the NEXT iteration's 15 loads in flight while
    // computing on the CURRENT buffer. The wave's memory pipe never drains
    // to empty (the structural flaw of all previous one-shot versions).
    v2f cur[DD], nxt[DD];
    #pragma unroll
    for (int d = 0; d < DD; ++d)
        cur[d] = *(const v2f*)(z + (size_t)d * NPIX + base);

    for (int it = 0; it < ITERS; ++it) {
        const size_t nbase = base + stride;
        if (it + 1 < ITERS) {                // wave-uniform branch
            #pragma unroll
            for (int d = 0; d < DD; ++d)
                nxt[d] = *(const v2f*)(z + (size_t)d * NPIX + nbase);
        }

        // ---- compute on cur, same numerics as passing R3/R4/R5 ----
        v2f zz = {0.f, 0.f};
        #pragma unroll
        for (int d = 0; d < DD; ++d)
            zz += cur[d] * cur[d];                          // v_pk_fma_f32

        v2f bestd2 = {3.0e38f, 3.0e38f};
        int bestk0 = 0, bestk1 = 0;

        #pragma unroll
        for (int k = 0; k < KK; ++k) {
            v2f cr = {0.f, 0.f};
            #pragma unroll
            for (int d = 0; d < DD; ++d) {
                const float vkd = vert[k * DD + d];         // SGPR broadcast
                cr += vkd * cur[d];                         // v_pk_fma_f32
            }
            const float vvk = vvS[k];
            // ref evaluation order: (zz - 2*cross) + vv; argmin on d^2
            // (sqrt is monotone + correctly rounded -> argmin/min commute).
            v2f d2 = (zz - 2.0f * cr) + vvk;
            if (d2.x < bestd2.x) { bestd2.x = d2.x; bestk0 = k; }  // first-min
            if (d2.y < bestd2.y) { bestd2.y = d2.y; bestk1 = k; }
        }

        v2f xo, dm;
        xo.x = (float)bestk0;
        xo.y = (float)bestk1;
        dm.x = sqrtf(fmaxf(bestd2.x, 0.0f));
        dm.y = sqrtf(fmaxf(bestd2.y, 0.0f));

        // nt stores: out is write-once — don't evict L3-resident z.
        __builtin_nontemporal_store(xo, (v2f*)(out + base));
        __builtin_nontemporal_store(dm, (v2f*)(out + NPIX + base));

        // rotate buffers
        #pragma unroll
        for (int d = 0; d < DD; ++d) cur[d] = nxt[d];
        base = nbase;
    }
}

extern "C" void kernel_launch(void* const* d_in, const int* in_sizes, int n_in,
                              void* d_out, int out_size, void* d_ws, size_t ws_size,
                              hipStream_t stream) {
    const float* z    = (const float*)d_in[0];   // (15, 2048, 2048) fp32
    const float* vert = (const float*)d_in[1];   // (16, 15) fp32
    float* out = (float*)d_out;                  // 2 * NPIX floats

    gum_kernel<<<NBLK, NTHR, 0, stream>>>(z, vert, out);
}